// Round 1
// baseline (579.629 us; speedup 1.0000x reference)
//
#include <hip/hip_runtime.h>
#include <math.h>

#define DIMC 1024
#define BB   8
#define LL   2048
#define ACTC 256
#define HIDC 256
#define EPSV 1e-6f
#define MROWS (BB * LL)   // 16384

typedef __bf16 bf16x8 __attribute__((ext_vector_type(8)));
typedef float  f32x4  __attribute__((ext_vector_type(4)));

__device__ __forceinline__ unsigned short f2bf(float f) {
    union { float f; unsigned int u; } v; v.f = f;
    unsigned int u = v.u + 0x7fffu + ((v.u >> 16) & 1u);
    return (unsigned short)(u >> 16);
}

// ---------------- weight convert ----------------
__global__ void k_f32_to_bf16(const float* __restrict__ in, unsigned short* __restrict__ out, int n) {
    int i = blockIdx.x * blockDim.x + threadIdx.x;
    int stride = gridDim.x * blockDim.x;
    for (; i < n; i += stride) out[i] = f2bf(in[i]);
}

// ---------------- RMSNorm: one block per row ----------------
__global__ __launch_bounds__(256) void k_rmsnorm(const float* __restrict__ x,
                                                 const float* __restrict__ w,
                                                 float* __restrict__ xn) {
    int m = blockIdx.x;
    int t = threadIdx.x;
    const float4* xr = (const float4*)(x + (size_t)m * DIMC);
    float4 v = xr[t];
    float ss = v.x*v.x + v.y*v.y + v.z*v.z + v.w*v.w;
#pragma unroll
    for (int off = 32; off > 0; off >>= 1) ss += __shfl_down(ss, off, 64);
    __shared__ float sred[4];
    if ((t & 63) == 0) sred[t >> 6] = ss;
    __syncthreads();
    float tot = sred[0] + sred[1] + sred[2] + sred[3];
    float rinv = 1.0f / sqrtf(tot * (1.0f / DIMC) + EPSV);
    const float4* wr = (const float4*)w;
    float4 wv = wr[t];
    float4 o;
    o.x = wv.x * v.x * rinv; o.y = wv.y * v.y * rinv;
    o.z = wv.z * v.z * rinv; o.w = wv.w * v.w * rinv;
    ((float4*)(xn + (size_t)m * DIMC))[t] = o;
}

// ---------------- depthwise conv K=5, zero-pad, output bf16 ----------------
__global__ __launch_bounds__(256) void k_dwconv(const float* __restrict__ xn,
                                                const float* __restrict__ dww,
                                                const float* __restrict__ dwb,
                                                unsigned short* __restrict__ xc) {
    int m = blockIdx.x;          // b*LL + l
    int l = m & (LL - 1);
    int t = threadIdx.x;         // channel group of 4
    int c0 = t * 4;
    float wgt[4][5];
#pragma unroll
    for (int j = 0; j < 4; ++j)
#pragma unroll
        for (int k = 0; k < 5; ++k) wgt[j][k] = dww[(c0 + j) * 5 + k];
    float4 bv = ((const float4*)dwb)[t];
    float acc[4] = {bv.x, bv.y, bv.z, bv.w};
#pragma unroll
    for (int k = 0; k < 5; ++k) {
        int ll = l + k - 2;
        if (ll < 0 || ll >= LL) continue;
        float4 v = ((const float4*)(xn + (size_t)(m + k - 2) * DIMC))[t];
        acc[0] += v.x * wgt[0][k];
        acc[1] += v.y * wgt[1][k];
        acc[2] += v.z * wgt[2][k];
        acc[3] += v.w * wgt[3][k];
    }
    uint2 o;
    o.x = (unsigned)f2bf(acc[0]) | ((unsigned)f2bf(acc[1]) << 16);
    o.y = (unsigned)f2bf(acc[2]) | ((unsigned)f2bf(acc[3]) << 16);
    ((uint2*)(xc + (size_t)m * DIMC))[t] = o;
}

// ---------------- sequential scan: h = a*h + b*x over L ----------------
__global__ __launch_bounds__(256) void k_scan(const float* __restrict__ xn,
                                              const float* __restrict__ alpha,
                                              const float* __restrict__ beta,
                                              float* __restrict__ hs) {
    int b = blockIdx.x;
    int c = threadIdx.x;
    float a = alpha[c], bt = beta[c];
    const float* p = xn + (size_t)b * LL * DIMC + c;
    float* q = hs + (size_t)b * LL * ACTC + c;
    float h = 0.0f;
    for (int l = 0; l < LL; ++l) {
        h = a * h + bt * p[(size_t)l * DIMC];
        q[(size_t)l * ACTC] = h;
    }
}

// ---------------- MFMA GEMM, C = A(MxK) * B^T(NxK), fused epilogues ----------------
// MODE 0: pw   — v = acc + bias0[n] + (n<ACT ? hs[m,n] : xn[m,n]); outf,outb
// MODE 1: glu  — v = add0 + sigmoid(acc0+bias0)*tanh(acc1+bias1);  outf,outb
// MODE 2: down — v = gelu_exact(acc + bias0);                       outb
// MODE 3: up   — v = add0 + acc + bias0 + add1;                     outf (d_out)
#define TM 128
#define TN 128
#define BKK 32

#define GLOAD_LDS(gp, lp) \
    __builtin_amdgcn_global_load_lds((const __attribute__((address_space(1))) unsigned int*)(gp), \
                                     (__attribute__((address_space(3))) unsigned int*)(lp), 16, 0, 0)

template<int MODE>
__global__ __launch_bounds__(256, 2) void k_gemm(
        const unsigned short* __restrict__ A,
        const unsigned short* __restrict__ B0,
        const unsigned short* __restrict__ B1,
        const float* __restrict__ bias0,
        const float* __restrict__ bias1,
        const float* __restrict__ add0,
        const float* __restrict__ add1,
        float* __restrict__ outf,
        unsigned short* __restrict__ outb,
        int M, int N, int K)
{
    __shared__ unsigned short sA[TM * BKK];
    __shared__ unsigned short sB0[TN * BKK];
    __shared__ unsigned short sB1[(MODE == 1) ? TN * BKK : 4];

    int t = threadIdx.x;
    int m0 = blockIdx.y * TM;
    int n0 = blockIdx.x * TN;
    int w = t >> 6, lane = t & 63;
    int wm = (w >> 1) * 64, wn = (w & 1) * 64;
    int quad = lane >> 4, lm = lane & 15;

    f32x4 zero = {0.f, 0.f, 0.f, 0.f};
    f32x4 acc0[4][4];
    f32x4 acc1[(MODE == 1) ? 4 : 1][(MODE == 1) ? 4 : 1];
#pragma unroll
    for (int i = 0; i < 4; ++i)
#pragma unroll
        for (int j = 0; j < 4; ++j) acc0[i][j] = zero;
    if constexpr (MODE == 1) {
#pragma unroll
        for (int i = 0; i < 4; ++i)
#pragma unroll
            for (int j = 0; j < 4; ++j) acc1[i][j] = zero;
    }

    for (int k0 = 0; k0 < K; k0 += BKK) {
        __syncthreads();
#pragma unroll
        for (int c = 0; c < 2; ++c) {
            int i = t + c * 256;
            int r = i >> 2, k8 = (i & 3) << 3;
            GLOAD_LDS(A  + (size_t)(m0 + r) * K + k0 + k8, &sA[i * 8]);
            GLOAD_LDS(B0 + (size_t)(n0 + r) * K + k0 + k8, &sB0[i * 8]);
            if constexpr (MODE == 1)
                GLOAD_LDS(B1 + (size_t)(n0 + r) * K + k0 + k8, &sB1[i * 8]);
        }
        __syncthreads();

        bf16x8 af[4], bf0[4];
#pragma unroll
        for (int i = 0; i < 4; ++i) {
            af[i]  = *(const bf16x8*)(&sA [(wm + i * 16 + lm) * BKK + quad * 8]);
            bf0[i] = *(const bf16x8*)(&sB0[(wn + i * 16 + lm) * BKK + quad * 8]);
        }
        if constexpr (MODE == 1) {
            bf16x8 bf1[4];
#pragma unroll
            for (int i = 0; i < 4; ++i)
                bf1[i] = *(const bf16x8*)(&sB1[(wn + i * 16 + lm) * BKK + quad * 8]);
#pragma unroll
            for (int mi = 0; mi < 4; ++mi)
#pragma unroll
                for (int ni = 0; ni < 4; ++ni) {
                    acc0[mi][ni] = __builtin_amdgcn_mfma_f32_16x16x32_bf16(af[mi], bf0[ni], acc0[mi][ni], 0, 0, 0);
                    acc1[mi][ni] = __builtin_amdgcn_mfma_f32_16x16x32_bf16(af[mi], bf1[ni], acc1[mi][ni], 0, 0, 0);
                }
        } else {
#pragma unroll
            for (int mi = 0; mi < 4; ++mi)
#pragma unroll
                for (int ni = 0; ni < 4; ++ni)
                    acc0[mi][ni] = __builtin_amdgcn_mfma_f32_16x16x32_bf16(af[mi], bf0[ni], acc0[mi][ni], 0, 0, 0);
        }
    }

#pragma unroll
    for (int mi = 0; mi < 4; ++mi) {
#pragma unroll
        for (int ni = 0; ni < 4; ++ni) {
            int n = n0 + wn + ni * 16 + lm;
#pragma unroll
            for (int j = 0; j < 4; ++j) {
                int m = m0 + wm + mi * 16 + quad * 4 + j;
                size_t idx = (size_t)m * N + n;
                float v = acc0[mi][ni][j];
                if constexpr (MODE == 0) {
                    v += bias0[n];
                    v += (n < ACTC) ? add0[(size_t)m * ACTC + n] : add1[(size_t)m * DIMC + n];
                    outf[idx] = v; outb[idx] = f2bf(v);
                } else if constexpr (MODE == 1) {
                    float u1 = v + bias0[n];
                    float u2 = acc1[mi][ni][j] + bias1[n];
                    float s  = 1.0f / (1.0f + expf(-u1));
                    float r  = add0[idx] + s * tanhf(u2);
                    outf[idx] = r; outb[idx] = f2bf(r);
                } else if constexpr (MODE == 2) {
                    float u = v + bias0[n];
                    float g = 0.5f * u * (1.0f + erff(u * 0.70710678118654752f));
                    outb[idx] = f2bf(g);
                } else {
                    outf[idx] = add0[idx] + v + bias0[n] + add1[idx];
                }
            }
        }
    }
}

extern "C" void kernel_launch(void* const* d_in, const int* in_sizes, int n_in,
                              void* d_out, int out_size, void* d_ws, size_t ws_size,
                              hipStream_t stream) {
    (void)in_sizes; (void)n_in; (void)out_size; (void)ws_size;
    const float* x      = (const float*)d_in[0];
    const float* norm_w = (const float*)d_in[1];
    const float* dw_w   = (const float*)d_in[2];
    const float* dw_b   = (const float*)d_in[3];
    const float* pw_w   = (const float*)d_in[4];
    const float* pw_b   = (const float*)d_in[5];
    const float* alpha  = (const float*)d_in[6];
    const float* beta   = (const float*)d_in[7];
    const float* W1_w   = (const float*)d_in[8];
    const float* W1_b   = (const float*)d_in[9];
    const float* W2_w   = (const float*)d_in[10];
    const float* W2_b   = (const float*)d_in[11];
    const float* down_w = (const float*)d_in[12];
    const float* down_b = (const float*)d_in[13];
    const float* up_w   = (const float*)d_in[14];
    const float* up_b   = (const float*)d_in[15];

    char* ws = (char*)d_ws;
    // layout (bytes):
    //   [0,64M)      xn fp32            (reused as y2 fp32 after pw epilogue)
    //   [64M,96M)    xc bf16            (reused as y2 bf16)
    //   [96M,112M)   hs fp32 16M        (reused as gelu-act bf16 8M)
    //   [112M,176M)  y1 fp32
    //   [176M,208M)  y1 bf16
    //   [208M, +7M)  bf16 weights
    float*          xn  = (float*)(ws);
    unsigned short* xc  = (unsigned short*)(ws + 67108864ull);
    float*          hs  = (float*)(ws + 100663296ull);
    float*          y1f = (float*)(ws + 117440512ull);
    unsigned short* y1b = (unsigned short*)(ws + 184549376ull);
    unsigned short* wpw = (unsigned short*)(ws + 218103808ull);
    unsigned short* w1b = wpw + 1048576;
    unsigned short* w2b = w1b + 1048576;
    unsigned short* wdn = w2b + 1048576;
    unsigned short* wup = wdn + 262144;

    float*          y2f  = xn;
    unsigned short* y2b  = xc;
    unsigned short* gact = (unsigned short*)hs;

    k_f32_to_bf16<<<1024, 256, 0, stream>>>(pw_w,   wpw, DIMC * DIMC);
    k_f32_to_bf16<<<1024, 256, 0, stream>>>(W1_w,   w1b, DIMC * DIMC);
    k_f32_to_bf16<<<1024, 256, 0, stream>>>(W2_w,   w2b, DIMC * DIMC);
    k_f32_to_bf16<<<256,  256, 0, stream>>>(down_w, wdn, HIDC * DIMC);
    k_f32_to_bf16<<<256,  256, 0, stream>>>(up_w,   wup, DIMC * HIDC);

    k_rmsnorm<<<MROWS, 256, 0, stream>>>(x, norm_w, xn);
    k_dwconv <<<MROWS, 256, 0, stream>>>(xn, dw_w, dw_b, xc);
    k_scan   <<<BB, ACTC, 0, stream>>>(xn, alpha, beta, hs);

    dim3 g1(DIMC / TN, MROWS / TM);
    dim3 g2(HIDC / TN, MROWS / TM);
    // pw: y1 = xc @ pw_w^T + pw_b + concat(hs, xn_tail)
    k_gemm<0><<<g1, 256, 0, stream>>>(xc, wpw, nullptr, pw_b, nullptr, hs, xn, y1f, y1b, MROWS, DIMC, DIMC);
    // glu: y2 = y1 + sigmoid(y1@W1^T+b1)*tanh(y1@W2^T+b2)
    k_gemm<1><<<g1, 256, 0, stream>>>(y1b, w1b, w2b, W1_b, W2_b, y1f, nullptr, y2f, y2b, MROWS, DIMC, DIMC);
    // down: g = gelu(y2 @ down^T + down_b)
    k_gemm<2><<<g2, 256, 0, stream>>>(y2b, wdn, nullptr, down_b, nullptr, nullptr, nullptr, nullptr, gact, MROWS, HIDC, DIMC);
    // up: out = y2 + g @ up^T + up_b + x
    k_gemm<3><<<g1, 256, 0, stream>>>(gact, wup, nullptr, up_b, nullptr, y2f, x, (float*)d_out, nullptr, MROWS, DIMC, HIDC);
}